// Round 5
// baseline (1017.608 us; speedup 1.0000x reference)
//
#include <hip/hip_runtime.h>
#include <math.h>

#define N_NODES 50000
#define N_EDGES 1600000
#define NBATCH  64
#define INCH    128
#define HEADS   8
#define HD      8
#define GH      64
#define HIDDEN  64
#define NC      10
#define NEG_SLOPE 0.2f
#define BN_EPS  1e-5f

#define SCAN_TPB 1024
#define NTILES   ((N_NODES + SCAN_TPB - 1) / SCAN_TPB)   // 49

typedef unsigned short ushort_t;
typedef unsigned int uint_t;

__device__ __forceinline__ ushort_t f2bf(float f) {
  uint_t u = __float_as_uint(f);
  uint_t r = (u + 0x7fffu + ((u >> 16) & 1u)) >> 16;   // RNE
  return (ushort_t)r;
}
__device__ __forceinline__ float bf2f(ushort_t h) {
  return __uint_as_float(((uint_t)h) << 16);
}

// ---------------- edge pass: gaussian weights + per-dst count/sum ----------------
__global__ __launch_bounds__(256) void edge_kernel(
    const int* __restrict__ ei, const float* __restrict__ raw,
    float* __restrict__ ea, float* __restrict__ easum, int* __restrict__ cnt) {
  int e = blockIdx.x * blockDim.x + threadIdx.x;
  if (e >= N_EDGES) return;
  int s = ei[e], d = ei[N_EDGES + e];
  float dx = raw[s*3+0] - raw[d*3+0];
  float dy = raw[s*3+1] - raw[d*3+1];
  float dz = raw[s*3+2] - raw[d*3+2];
  float w = __expf(-2.0f * (dx*dx + dy*dy + dz*dz));   // sigma=0.5 -> /(2*0.25)
  ea[e] = w;
  atomicAdd(&easum[d], w);
  atomicAdd(&cnt[d], 1);
}

// ---------------- CSR build: 3-phase scan + scatter ----------------
__global__ __launch_bounds__(SCAN_TPB) void scan_part(
    const int* __restrict__ cnt, const float* __restrict__ easum,
    int* __restrict__ rowptr, float* __restrict__ loopat, int* __restrict__ bsum) {
  __shared__ int s[SCAN_TPB];
  int t = threadIdx.x;
  int i = blockIdx.x * SCAN_TPB + t;
  int v = (i < N_NODES) ? cnt[i] : 0;
  s[t] = v; __syncthreads();
  for (int off = 1; off < SCAN_TPB; off <<= 1) {
    int u = (t >= off) ? s[t - off] : 0;
    __syncthreads();
    s[t] += u;
    __syncthreads();
  }
  if (i < N_NODES) {
    rowptr[i] = s[t] - v;                          // block-local exclusive
    loopat[i] = easum[i] / fmaxf((float)v, 1.0f);  // self-loop attr (mean)
  }
  if (t == SCAN_TPB - 1) bsum[blockIdx.x] = s[t];
}

__global__ __launch_bounds__(64) void scan_top(int* __restrict__ bsum, int* __restrict__ rowptr) {
  int t = threadIdx.x;
  int v = (t < NTILES) ? bsum[t] : 0;
  int orig = v;
  for (int off = 1; off < 64; off <<= 1) {
    int u = __shfl_up(v, off);
    if (t >= off) v += u;
  }
  if (t < NTILES) bsum[t] = v - orig;   // exclusive block offsets
  if (t == 0) rowptr[N_NODES] = N_EDGES;
}

__global__ __launch_bounds__(SCAN_TPB) void scan_add(int* __restrict__ rowptr, const int* __restrict__ bsum) {
  int i = blockIdx.x * SCAN_TPB + threadIdx.x;
  if (i < N_NODES) rowptr[i] += bsum[blockIdx.x];
}

__global__ __launch_bounds__(256) void scatter_kernel(
    const int* __restrict__ ei, const float* __restrict__ ea,
    const int* __restrict__ rowptr, int* __restrict__ cnt2,
    int* __restrict__ csr_src, float* __restrict__ csr_ea) {
  int e = blockIdx.x * blockDim.x + threadIdx.x;
  if (e >= N_EDGES) return;
  int s = ei[e], d = ei[N_EDGES + e];
  int pos = rowptr[d] + atomicAdd(&cnt2[d], 1);
  csr_src[pos] = s;
  csr_ea[pos] = ea[e];
}

// ---------------- GEMM1: h1 = x @ W1 (bf16 rows), fused al_src1/al_dst1 ----------------
__global__ __launch_bounds__(256) void gemm1_kernel(
    const float* __restrict__ x, const float* __restrict__ W1,
    const float* __restrict__ asrc, const float* __restrict__ adst,
    ushort_t* __restrict__ h1b, float* __restrict__ als, float* __restrict__ ald) {
  __shared__ float w[INCH * GH];   // 32 KB
  for (int i = threadIdx.x; i < INCH * GH / 4; i += blockDim.x)
    ((float4*)w)[i] = ((const float4*)W1)[i];
  __syncthreads();
  int lane = threadIdx.x & 63;
  int waveG = __builtin_amdgcn_readfirstlane((blockIdx.x * blockDim.x + threadIdx.x) >> 6);
  int nWaves = (gridDim.x * blockDim.x) >> 6;
  float a_s = asrc[lane];
  float a_d = adst[lane];
  for (int base = waveG * 4; base < N_NODES; base += nWaves * 4) {   // N % 4 == 0
    float acc[4] = {0.f, 0.f, 0.f, 0.f};
    #pragma unroll 8
    for (int k = 0; k < INCH; ++k) {
      float wv = w[k * GH + lane];
      #pragma unroll
      for (int j = 0; j < 4; ++j)
        acc[j] = fmaf(x[(size_t)(base + j) * INCH + k], wv, acc[j]);
    }
    #pragma unroll
    for (int j = 0; j < 4; ++j) {
      int n = base + j;
      float hv = acc[j];
      h1b[(size_t)n * GH + lane] = f2bf(hv);
      float ps = hv * a_s, pd = hv * a_d;
      ps += __shfl_xor(ps, 1); ps += __shfl_xor(ps, 2); ps += __shfl_xor(ps, 4);
      pd += __shfl_xor(pd, 1); pd += __shfl_xor(pd, 2); pd += __shfl_xor(pd, 4);
      if ((lane & 7) == 0) {
        als[n * HEADS + (lane >> 3)] = ps;
        ald[n * HEADS + (lane >> 3)] = pd;
      }
    }
  }
}

// ---------------- conv1: chunked lane-parallel softmax + 8-deep bf16 gather ----------------
__global__ __launch_bounds__(256) void conv1_kernel(
    const ushort_t* __restrict__ h1b, const float* __restrict__ als,
    const float* __restrict__ ald, const float* __restrict__ We,
    const float* __restrict__ ae, const int* __restrict__ rowptr,
    const int* __restrict__ csr_src, const float* __restrict__ csr_ea,
    const float* __restrict__ loopat, const float* __restrict__ bias,
    const float* __restrict__ gamma, const float* __restrict__ beta,
    const float* __restrict__ rm, const float* __restrict__ rv,
    float* __restrict__ h2) {
  __shared__ int   src_lds[4][64];
  __shared__ float ea_lds[4][64];
  __shared__ float ex_lds[4][512];   // [edge][head]
  int lane = threadIdx.x & 63;
  int w = threadIdx.x >> 6;
  int n = blockIdx.x * 4 + w;
  if (n >= N_NODES) return;
  int hA = lane & 7;        // phase-A head
  int e8 = lane >> 3;       // phase-A edge-in-group
  int hB = lane >> 3;       // phase-B head
  float ceA = 0.f;
  #pragma unroll
  for (int d = 0; d < HD; ++d) ceA = fmaf(We[hA * HD + d], ae[hA * HD + d], ceA);
  float aldnA = ald[n * HEADS + hA];
  int jb = rowptr[n], je = rowptr[n + 1];
  float m = -1e30f, ssum = 0.f;   // phase-A head layout
  float acc = 0.f;                // phase-B (h,d) layout
  for (int cb = jb; cb < je; cb += 64) {
    int cnt = je - cb; if (cnt > 64) cnt = 64;
    int idx = cb + lane;
    bool vld = lane < cnt;
    src_lds[w][lane] = vld ? csr_src[idx] : 0;
    ea_lds[w][lane]  = vld ? csr_ea[idx] : 0.f;
    float lg[8];
    #pragma unroll
    for (int sub = 0; sub < 8; ++sub) {
      int eo = sub * 8 + e8;
      int s = src_lds[w][eo];
      float l = als[s * HEADS + hA] + aldnA + ea_lds[w][eo] * ceA;
      l = (l >= 0.f) ? l : NEG_SLOPE * l;
      lg[sub] = (eo < cnt) ? l : -1e30f;
    }
    float cm = lg[0];
    #pragma unroll
    for (int sub = 1; sub < 8; ++sub) cm = fmaxf(cm, lg[sub]);
    cm = fmaxf(cm, __shfl_xor(cm, 8));
    cm = fmaxf(cm, __shfl_xor(cm, 16));
    cm = fmaxf(cm, __shfl_xor(cm, 32));
    float nm = fmaxf(m, cm);
    float sc = __expf(m - nm);
    float csum = 0.f;
    #pragma unroll
    for (int sub = 0; sub < 8; ++sub) {
      float ex = __expf(lg[sub] - nm);
      csum += ex;
      ex_lds[w][sub * 64 + lane] = ex;   // == [ (sub*8+e8)*8 + hA ]
    }
    csum += __shfl_xor(csum, 8);
    csum += __shfl_xor(csum, 16);
    csum += __shfl_xor(csum, 32);
    ssum = ssum * sc + csum;
    m = nm;
    // phase B: rescale + 8-deep independent bf16 gathers
    float scB = __shfl(sc, hB);
    acc *= scB;
    int j = 0;
    for (; j + 7 < cnt; j += 8) {
      int s0 = src_lds[w][j],   s1 = src_lds[w][j+1];
      int s2 = src_lds[w][j+2], s3 = src_lds[w][j+3];
      int s4 = src_lds[w][j+4], s5 = src_lds[w][j+5];
      int s6 = src_lds[w][j+6], s7 = src_lds[w][j+7];
      ushort_t v0 = h1b[(size_t)s0 * GH + lane];
      ushort_t v1 = h1b[(size_t)s1 * GH + lane];
      ushort_t v2 = h1b[(size_t)s2 * GH + lane];
      ushort_t v3 = h1b[(size_t)s3 * GH + lane];
      ushort_t v4 = h1b[(size_t)s4 * GH + lane];
      ushort_t v5 = h1b[(size_t)s5 * GH + lane];
      ushort_t v6 = h1b[(size_t)s6 * GH + lane];
      ushort_t v7 = h1b[(size_t)s7 * GH + lane];
      acc = fmaf(ex_lds[w][(j  )*8 + hB], bf2f(v0), acc);
      acc = fmaf(ex_lds[w][(j+1)*8 + hB], bf2f(v1), acc);
      acc = fmaf(ex_lds[w][(j+2)*8 + hB], bf2f(v2), acc);
      acc = fmaf(ex_lds[w][(j+3)*8 + hB], bf2f(v3), acc);
      acc = fmaf(ex_lds[w][(j+4)*8 + hB], bf2f(v4), acc);
      acc = fmaf(ex_lds[w][(j+5)*8 + hB], bf2f(v5), acc);
      acc = fmaf(ex_lds[w][(j+6)*8 + hB], bf2f(v6), acc);
      acc = fmaf(ex_lds[w][(j+7)*8 + hB], bf2f(v7), acc);
    }
    for (; j < cnt; ++j) {
      int s0 = src_lds[w][j];
      acc = fmaf(ex_lds[w][j*8 + hB], bf2f(h1b[(size_t)s0 * GH + lane]), acc);
    }
  }
  float mB = __shfl(m, hB);
  float sB = __shfl(ssum, hB);
  float ceB = 0.f;
  #pragma unroll
  for (int d = 0; d < HD; ++d) ceB = fmaf(We[hB * HD + d], ae[hB * HD + d], ceB);
  {
    float lg = als[n * HEADS + hB] + ald[n * HEADS + hB] + loopat[n] * ceB;
    lg = (lg >= 0.f) ? lg : NEG_SLOPE * lg;
    float nm = fmaxf(mB, lg);
    float r = __expf(mB - nm);
    float p = __expf(lg - nm);
    sB = sB * r + p;
    acc = acc * r + p * bf2f(h1b[(size_t)n * GH + lane]);
  }
  float outv = acc / sB + bias[lane];
  outv = (outv - rm[lane]) * (gamma[lane] * rsqrtf(rv[lane] + BN_EPS)) + beta[lane];
  outv = (outv > 0.f) ? outv : expm1f(outv);
  h2[(size_t)n * GH + lane] = outv;
}

// ---------------- GEMM2: h2m = h2 @ W2 (bf16 rows), fused al_src2/al_dst2 ----------------
__global__ __launch_bounds__(256) void gemm2_kernel(
    const float* __restrict__ x, const float* __restrict__ W2,
    const float* __restrict__ asrc, const float* __restrict__ adst,
    ushort_t* __restrict__ h2mb, float* __restrict__ als, float* __restrict__ ald) {
  __shared__ float w[HIDDEN * HIDDEN];   // 16 KB
  for (int i = threadIdx.x; i < HIDDEN * HIDDEN / 4; i += blockDim.x)
    ((float4*)w)[i] = ((const float4*)W2)[i];
  __syncthreads();
  int lane = threadIdx.x & 63;
  int waveG = __builtin_amdgcn_readfirstlane((blockIdx.x * blockDim.x + threadIdx.x) >> 6);
  int nWaves = (gridDim.x * blockDim.x) >> 6;
  float a_s = asrc[lane];
  float a_d = adst[lane];
  for (int base = waveG * 4; base < N_NODES; base += nWaves * 4) {
    float acc[4] = {0.f, 0.f, 0.f, 0.f};
    #pragma unroll 8
    for (int k = 0; k < HIDDEN; ++k) {
      float wv = w[k * HIDDEN + lane];
      #pragma unroll
      for (int j = 0; j < 4; ++j)
        acc[j] = fmaf(x[(size_t)(base + j) * HIDDEN + k], wv, acc[j]);
    }
    #pragma unroll
    for (int j = 0; j < 4; ++j) {
      int n = base + j;
      float hv = acc[j];
      h2mb[(size_t)n * HIDDEN + lane] = f2bf(hv);
      float ps = hv * a_s, pd = hv * a_d;
      #pragma unroll
      for (int off = 1; off < 64; off <<= 1) {
        ps += __shfl_xor(ps, off);
        pd += __shfl_xor(pd, off);
      }
      if (lane == 0) { als[n] = ps; ald[n] = pd; }
    }
  }
}

// ---------------- conv2 (heads=1): lane-parallel softmax + 8-deep bf16 gather ----------------
__global__ __launch_bounds__(256) void conv2_kernel(
    const ushort_t* __restrict__ h2mb, const float* __restrict__ als,
    const float* __restrict__ ald, const float* __restrict__ We,
    const float* __restrict__ ae, const int* __restrict__ rowptr,
    const int* __restrict__ csr_src, const float* __restrict__ csr_ea,
    const float* __restrict__ loopat, const float* __restrict__ bias,
    const float* __restrict__ gamma, const float* __restrict__ beta,
    const float* __restrict__ rm, const float* __restrict__ rv,
    const int* __restrict__ batch,
    float* __restrict__ pool, int* __restrict__ cntg) {
  __shared__ int   src_lds[4][64];
  __shared__ float ex_lds[4][64];
  int lane = threadIdx.x & 63;
  int w = threadIdx.x >> 6;
  int n = blockIdx.x * 4 + (threadIdx.x >> 6);
  if (n >= N_NODES) return;
  float ce = We[lane] * ae[lane];
  #pragma unroll
  for (int off = 1; off < 64; off <<= 1) ce += __shfl_xor(ce, off);
  float aldn = ald[n];
  int jb = rowptr[n], je = rowptr[n + 1];
  float m = -1e30f, ssum = 0.f, acc = 0.f;
  for (int cb = jb; cb < je; cb += 64) {
    int cnt = je - cb; if (cnt > 64) cnt = 64;
    int idx = cb + lane;
    bool vld = lane < cnt;
    int sv = vld ? csr_src[idx] : 0;
    float eav = vld ? csr_ea[idx] : 0.f;
    src_lds[w][lane] = sv;
    float lg = als[sv] + aldn + eav * ce;
    lg = (lg >= 0.f) ? lg : NEG_SLOPE * lg;
    lg = vld ? lg : -1e30f;
    float cm = lg;
    cm = fmaxf(cm, __shfl_xor(cm, 1));  cm = fmaxf(cm, __shfl_xor(cm, 2));
    cm = fmaxf(cm, __shfl_xor(cm, 4));  cm = fmaxf(cm, __shfl_xor(cm, 8));
    cm = fmaxf(cm, __shfl_xor(cm, 16)); cm = fmaxf(cm, __shfl_xor(cm, 32));
    float nm = fmaxf(m, cm);
    float sc = __expf(m - nm);
    float ex = __expf(lg - nm);
    ex_lds[w][lane] = ex;
    float csum = ex;
    csum += __shfl_xor(csum, 1);  csum += __shfl_xor(csum, 2);
    csum += __shfl_xor(csum, 4);  csum += __shfl_xor(csum, 8);
    csum += __shfl_xor(csum, 16); csum += __shfl_xor(csum, 32);
    ssum = ssum * sc + csum;
    m = nm;
    acc *= sc;
    int j = 0;
    for (; j + 7 < cnt; j += 8) {
      int s0 = src_lds[w][j],   s1 = src_lds[w][j+1];
      int s2 = src_lds[w][j+2], s3 = src_lds[w][j+3];
      int s4 = src_lds[w][j+4], s5 = src_lds[w][j+5];
      int s6 = src_lds[w][j+6], s7 = src_lds[w][j+7];
      ushort_t v0 = h2mb[(size_t)s0 * HIDDEN + lane];
      ushort_t v1 = h2mb[(size_t)s1 * HIDDEN + lane];
      ushort_t v2 = h2mb[(size_t)s2 * HIDDEN + lane];
      ushort_t v3 = h2mb[(size_t)s3 * HIDDEN + lane];
      ushort_t v4 = h2mb[(size_t)s4 * HIDDEN + lane];
      ushort_t v5 = h2mb[(size_t)s5 * HIDDEN + lane];
      ushort_t v6 = h2mb[(size_t)s6 * HIDDEN + lane];
      ushort_t v7 = h2mb[(size_t)s7 * HIDDEN + lane];
      acc = fmaf(ex_lds[w][j  ], bf2f(v0), acc);
      acc = fmaf(ex_lds[w][j+1], bf2f(v1), acc);
      acc = fmaf(ex_lds[w][j+2], bf2f(v2), acc);
      acc = fmaf(ex_lds[w][j+3], bf2f(v3), acc);
      acc = fmaf(ex_lds[w][j+4], bf2f(v4), acc);
      acc = fmaf(ex_lds[w][j+5], bf2f(v5), acc);
      acc = fmaf(ex_lds[w][j+6], bf2f(v6), acc);
      acc = fmaf(ex_lds[w][j+7], bf2f(v7), acc);
    }
    for (; j < cnt; ++j) {
      acc = fmaf(ex_lds[w][j], bf2f(h2mb[(size_t)src_lds[w][j] * HIDDEN + lane]), acc);
    }
  }
  { // self loop
    float lg = als[n] + aldn + loopat[n] * ce;
    lg = (lg >= 0.f) ? lg : NEG_SLOPE * lg;
    float nm = fmaxf(m, lg);
    float r = __expf(m - nm);
    float p = __expf(lg - nm);
    ssum = ssum * r + p;
    acc  = acc  * r + p * bf2f(h2mb[(size_t)n * HIDDEN + lane]);
  }
  float outv = acc / ssum + bias[lane];
  outv = (outv - rm[lane]) * (gamma[lane] * rsqrtf(rv[lane] + BN_EPS)) + beta[lane];
  outv = (outv > 0.f) ? outv : expm1f(outv);
  int b = batch[n];
  atomicAdd(&pool[b * HIDDEN + lane], outv);
  if (lane == 0) atomicAdd(&cntg[b], 1);
}

// ---------------- classifier ----------------
__global__ __launch_bounds__(640) void final_kernel(
    const float* __restrict__ pool, const int* __restrict__ cntg,
    const float* __restrict__ Wc, const float* __restrict__ bc,
    float* __restrict__ out) {
  int t = threadIdx.x;
  if (t >= NBATCH * NC) return;
  int b = t / NC, c = t - b * NC;
  float inv = 1.0f / fmaxf((float)cntg[b], 1.0f);
  float s = bc[c];
  #pragma unroll
  for (int d = 0; d < HIDDEN; ++d)
    s = fmaf(pool[b * HIDDEN + d] * inv, Wc[d * NC + c], s);
  out[t] = s;
}

extern "C" void kernel_launch(void* const* d_in, const int* in_sizes, int n_in,
                              void* d_out, int out_size, void* d_ws, size_t ws_size,
                              hipStream_t stream) {
  const float* x     = (const float*)d_in[0];
  const float* raw   = (const float*)d_in[1];
  const int*   ei    = (const int*)  d_in[2];
  const int*   batch = (const int*)  d_in[3];
  const float* W1    = (const float*)d_in[4];
  const float* asrc1 = (const float*)d_in[5];
  const float* adst1 = (const float*)d_in[6];
  const float* We1   = (const float*)d_in[7];
  const float* ae1   = (const float*)d_in[8];
  const float* b1    = (const float*)d_in[9];
  const float* g1    = (const float*)d_in[10];
  const float* be1   = (const float*)d_in[11];
  const float* rm1   = (const float*)d_in[12];
  const float* rv1   = (const float*)d_in[13];
  const float* W2    = (const float*)d_in[14];
  const float* asrc2 = (const float*)d_in[15];
  const float* adst2 = (const float*)d_in[16];
  const float* We2   = (const float*)d_in[17];
  const float* ae2   = (const float*)d_in[18];
  const float* b2    = (const float*)d_in[19];
  const float* g2    = (const float*)d_in[20];
  const float* be2   = (const float*)d_in[21];
  const float* rm2   = (const float*)d_in[22];
  const float* rv2   = (const float*)d_in[23];
  const float* Wc    = (const float*)d_in[24];
  const float* bc    = (const float*)d_in[25];
  float* out = (float*)d_out;

  char* ws = (char*)d_ws;
  size_t off = 0;
  auto alloc = [&](size_t bytes) -> void* {
    void* p = ws + off;
    off += bytes;
    off = (off + 255) & ~(size_t)255;
    return p;
  };
  float*    ea      = (float*)   alloc((size_t)N_EDGES * 4);
  float*    csr_ea  = (float*)   alloc((size_t)N_EDGES * 4);
  int*      csr_src = (int*)     alloc((size_t)N_EDGES * 4);
  float*    easum   = (float*)   alloc((size_t)N_NODES * 4);
  int*      cnt     = (int*)     alloc((size_t)N_NODES * 4);
  int*      cnt2    = (int*)     alloc((size_t)N_NODES * 4);
  int*      rowptr  = (int*)     alloc((size_t)(N_NODES + 1) * 4);
  float*    loopat  = (float*)   alloc((size_t)N_NODES * 4);
  ushort_t* h1b     = (ushort_t*)alloc((size_t)N_NODES * GH * 2);
  float*    als1    = (float*)   alloc((size_t)N_NODES * HEADS * 4);
  float*    ald1    = (float*)   alloc((size_t)N_NODES * HEADS * 4);
  float*    h2      = (float*)   alloc((size_t)N_NODES * GH * 4);
  ushort_t* h2mb    = (ushort_t*)alloc((size_t)N_NODES * HIDDEN * 2);
  float*    als2    = (float*)   alloc((size_t)N_NODES * 4);
  float*    ald2    = (float*)   alloc((size_t)N_NODES * 4);
  int*      bsum    = (int*)     alloc(64 * 4);
  float*    pool    = (float*)   alloc((size_t)NBATCH * HIDDEN * 4);
  int*      cntg    = (int*)     alloc((size_t)NBATCH * 4);

  hipMemsetAsync(easum, 0, (size_t)N_NODES * 4, stream);
  hipMemsetAsync(cnt,   0, (size_t)N_NODES * 4, stream);
  hipMemsetAsync(cnt2,  0, (size_t)N_NODES * 4, stream);
  hipMemsetAsync(pool,  0, (size_t)NBATCH * HIDDEN * 4, stream);
  hipMemsetAsync(cntg,  0, (size_t)NBATCH * 4, stream);

  int egrid = (N_EDGES + 255) / 256;
  edge_kernel<<<egrid, 256, 0, stream>>>(ei, raw, ea, easum, cnt);
  scan_part<<<NTILES, SCAN_TPB, 0, stream>>>(cnt, easum, rowptr, loopat, bsum);
  scan_top<<<1, 64, 0, stream>>>(bsum, rowptr);
  scan_add<<<NTILES, SCAN_TPB, 0, stream>>>(rowptr, bsum);
  scatter_kernel<<<egrid, 256, 0, stream>>>(ei, ea, rowptr, cnt2, csr_src, csr_ea);

  gemm1_kernel<<<1024, 256, 0, stream>>>(x, W1, asrc1, adst1, h1b, als1, ald1);
  conv1_kernel<<<(N_NODES + 3) / 4, 256, 0, stream>>>(h1b, als1, ald1, We1, ae1,
      rowptr, csr_src, csr_ea, loopat, b1, g1, be1, rm1, rv1, h2);
  gemm2_kernel<<<1024, 256, 0, stream>>>(h2, W2, asrc2, adst2, h2mb, als2, ald2);
  conv2_kernel<<<(N_NODES + 3) / 4, 256, 0, stream>>>(h2mb, als2, ald2, We2, ae2,
      rowptr, csr_src, csr_ea, loopat, b2, g2, be2, rm2, rv2, batch, pool, cntg);
  final_kernel<<<1, 640, 0, stream>>>(pool, cntg, Wc, bc, out);
}

// Round 7
// 929.939 us; speedup vs baseline: 1.0943x; 1.0943x over previous
//
#include <hip/hip_runtime.h>
#include <math.h>

#define N_NODES 50000
#define N_EDGES 1600000
#define NBATCH  64
#define INCH    128
#define HEADS   8
#define HD      8
#define GH      64
#define HIDDEN  64
#define NC      10
#define NEG_SLOPE 0.2f
#define BN_EPS  1e-5f

#define SCAN_TPB 1024
#define NTILES   ((N_NODES + SCAN_TPB - 1) / SCAN_TPB)   // 49

typedef unsigned short ushort_t;
typedef unsigned int uint_t;

__device__ __forceinline__ ushort_t f2bf(float f) {
  uint_t u = __float_as_uint(f);
  uint_t r = (u + 0x7fffu + ((u >> 16) & 1u)) >> 16;   // RNE
  return (ushort_t)r;
}
// unpack 2 bf16 from one uint: low half -> .x, high half -> .y
__device__ __forceinline__ float2 upk(uint_t u) {
  return make_float2(__uint_as_float(u << 16), __uint_as_float(u & 0xffff0000u));
}

// ---------------- edge pass: gaussian weights + per-dst count/sum ----------------
__global__ __launch_bounds__(256) void edge_kernel(
    const int* __restrict__ ei, const float* __restrict__ raw,
    float* __restrict__ ea, float* __restrict__ easum, int* __restrict__ cnt) {
  int e = blockIdx.x * blockDim.x + threadIdx.x;
  if (e >= N_EDGES) return;
  int s = ei[e], d = ei[N_EDGES + e];
  float dx = raw[s*3+0] - raw[d*3+0];
  float dy = raw[s*3+1] - raw[d*3+1];
  float dz = raw[s*3+2] - raw[d*3+2];
  float w = __expf(-2.0f * (dx*dx + dy*dy + dz*dz));   // sigma=0.5 -> /(2*0.25)
  ea[e] = w;
  atomicAdd(&easum[d], w);
  atomicAdd(&cnt[d], 1);
}

// ---------------- CSR build: 3-phase scan + scatter ----------------
__global__ __launch_bounds__(SCAN_TPB) void scan_part(
    const int* __restrict__ cnt, const float* __restrict__ easum,
    int* __restrict__ rowptr, float* __restrict__ loopat, int* __restrict__ bsum) {
  __shared__ int s[SCAN_TPB];
  int t = threadIdx.x;
  int i = blockIdx.x * SCAN_TPB + t;
  int v = (i < N_NODES) ? cnt[i] : 0;
  s[t] = v; __syncthreads();
  for (int off = 1; off < SCAN_TPB; off <<= 1) {
    int u = (t >= off) ? s[t - off] : 0;
    __syncthreads();
    s[t] += u;
    __syncthreads();
  }
  if (i < N_NODES) {
    rowptr[i] = s[t] - v;                          // block-local exclusive
    loopat[i] = easum[i] / fmaxf((float)v, 1.0f);  // self-loop attr (mean)
  }
  if (t == SCAN_TPB - 1) bsum[blockIdx.x] = s[t];
}

__global__ __launch_bounds__(64) void scan_top(int* __restrict__ bsum, int* __restrict__ rowptr) {
  int t = threadIdx.x;
  int v = (t < NTILES) ? bsum[t] : 0;
  int orig = v;
  for (int off = 1; off < 64; off <<= 1) {
    int u = __shfl_up(v, off);
    if (t >= off) v += u;
  }
  if (t < NTILES) bsum[t] = v - orig;   // exclusive block offsets
  if (t == 0) rowptr[N_NODES] = N_EDGES;
}

__global__ __launch_bounds__(SCAN_TPB) void scan_add(int* __restrict__ rowptr, const int* __restrict__ bsum) {
  int i = blockIdx.x * SCAN_TPB + threadIdx.x;
  if (i < N_NODES) rowptr[i] += bsum[blockIdx.x];
}

__global__ __launch_bounds__(256) void scatter_kernel(
    const int* __restrict__ ei, const float* __restrict__ ea,
    const int* __restrict__ rowptr, int* __restrict__ cnt2,
    int* __restrict__ csr_src, float* __restrict__ csr_ea) {
  int e = blockIdx.x * blockDim.x + threadIdx.x;
  if (e >= N_EDGES) return;
  int s = ei[e], d = ei[N_EDGES + e];
  int pos = rowptr[d] + atomicAdd(&cnt2[d], 1);
  csr_src[pos] = s;
  csr_ea[pos] = ea[e];
}

// ---------------- GEMM1: h1 = x @ W1 (bf16 rows) ----------------
__global__ __launch_bounds__(256) void gemm1_kernel(
    const float* __restrict__ x, const float* __restrict__ W1,
    ushort_t* __restrict__ h1b) {
  __shared__ float w[INCH * GH];   // 32 KB
  for (int i = threadIdx.x; i < INCH * GH / 4; i += blockDim.x)
    ((float4*)w)[i] = ((const float4*)W1)[i];
  __syncthreads();
  int lane = threadIdx.x & 63;
  int waveG = __builtin_amdgcn_readfirstlane((blockIdx.x * blockDim.x + threadIdx.x) >> 6);
  int nWaves = (gridDim.x * blockDim.x) >> 6;
  for (int base = waveG * 4; base < N_NODES; base += nWaves * 4) {   // N % 4 == 0
    float acc[4] = {0.f, 0.f, 0.f, 0.f};
    #pragma unroll 8
    for (int k = 0; k < INCH; ++k) {
      float wv = w[k * GH + lane];
      #pragma unroll
      for (int j = 0; j < 4; ++j)
        acc[j] = fmaf(x[(size_t)(base + j) * INCH + k], wv, acc[j]);
    }
    #pragma unroll
    for (int j = 0; j < 4; ++j)
      h1b[(size_t)(base + j) * GH + lane] = f2bf(acc[j]);
  }
}

// ---------------- conv1: single-touch 4-edge-batched gather, per-head softmax ----------------
// lane = 16*q + i; quarter q handles edge (batch*4+q); lane i covers dims 4i..4i+3 (head i>>1).
// bf16 row = 64 bf16 = 128 B = 16 x uint2  (uint2 holds 4 bf16)
__global__ __launch_bounds__(256) void conv1_kernel(
    const ushort_t* __restrict__ h1b,
    const float* __restrict__ asrc, const float* __restrict__ adst,
    const float* __restrict__ We, const float* __restrict__ ae,
    const int* __restrict__ rowptr,
    const int* __restrict__ csr_src, const float* __restrict__ csr_ea,
    const float* __restrict__ loopat, const float* __restrict__ bias,
    const float* __restrict__ gamma, const float* __restrict__ beta,
    const float* __restrict__ rm, const float* __restrict__ rv,
    float* __restrict__ h2) {
  __shared__ int   src_lds[4][64];
  __shared__ float ea_lds[4][64];
  int l = threadIdx.x & 63;
  int w = threadIdx.x >> 6;
  int n = blockIdx.x * 4 + w;
  if (n >= N_NODES) return;
  int i = l & 15;
  int q = l >> 4;
  const float4 as4 = ((const float4*)asrc)[i];
  const float4 ad4 = ((const float4*)adst)[i];
  float4 we4 = ((const float4*)We)[i];
  float4 ae4 = ((const float4*)ae)[i];
  float ce = we4.x*ae4.x + we4.y*ae4.y + we4.z*ae4.z + we4.w*ae4.w;
  ce += __shfl_xor(ce, 1);                     // per-head (pair) edge coeff
  const uint2* tab = (const uint2*)h1b;        // row = 16 x uint2
  // own row: self als / aldn (per head)
  uint2 uself = tab[(size_t)n * 16 + i];
  float2 s01 = upk(uself.x), s23 = upk(uself.y);
  float als_s = s01.x*as4.x + s01.y*as4.y + s23.x*as4.z + s23.y*as4.w;
  als_s += __shfl_xor(als_s, 1);
  float aldn  = s01.x*ad4.x + s01.y*ad4.y + s23.x*ad4.z + s23.y*ad4.w;
  aldn += __shfl_xor(aldn, 1);
  int jb = rowptr[n], je = rowptr[n + 1];
  float m = -1e30f, ssum = 0.f;
  float a0 = 0.f, a1 = 0.f, a2 = 0.f, a3 = 0.f;
  for (int cb = jb; cb < je; cb += 64) {
    int cnt = je - cb; if (cnt > 64) cnt = 64;
    int idx = cb + l;
    bool vld = l < cnt;
    src_lds[w][l] = vld ? csr_src[idx] : 0;
    ea_lds[w][l]  = vld ? csr_ea[idx] : 0.f;
    int nb = (cnt + 3) >> 2;
    // prefetch batch 0
    int j0 = q;
    int s0 = (j0 < cnt) ? src_lds[w][j0] : 0;
    uint2 rcur = tab[(size_t)s0 * 16 + i];
    for (int b = 0; b < nb; ++b) {
      uint2 rnext = rcur;
      if (b + 1 < nb) {
        int jn = ((b + 1) << 2) + q;
        int sn = (jn < cnt) ? src_lds[w][jn] : 0;
        rnext = tab[(size_t)sn * 16 + i];
      }
      int j = (b << 2) + q;
      bool val = j < cnt;
      float eav = val ? ea_lds[w][j] : 0.f;
      float2 p01 = upk(rcur.x), p23 = upk(rcur.y);
      float dp = p01.x*as4.x + p01.y*as4.y + p23.x*as4.z + p23.y*as4.w;
      dp += __shfl_xor(dp, 1);                 // per-head als of this edge
      float lg = dp + aldn + eav * ce;
      lg = (lg >= 0.f) ? lg : NEG_SLOPE * lg;
      lg = val ? lg : -1e30f;
      float bm = fmaxf(lg, __shfl_xor(lg, 16));
      bm = fmaxf(bm, __shfl_xor(bm, 32));      // per-head max over 4 edges
      float nm = fmaxf(m, bm);
      float sc = __expf(m - nm);
      float p  = __expf(lg - nm);
      float ps = p;
      ps += __shfl_xor(ps, 16);
      ps += __shfl_xor(ps, 32);                // per-head sum over 4 edges
      ssum = ssum * sc + ps;
      m = nm;
      a0 = a0 * sc + p * p01.x;
      a1 = a1 * sc + p * p01.y;
      a2 = a2 * sc + p * p23.x;
      a3 = a3 * sc + p * p23.y;
      rcur = rnext;
    }
  }
  // fold quarters (linear; shared per-head scales)
  a0 += __shfl_xor(a0, 16); a0 += __shfl_xor(a0, 32);
  a1 += __shfl_xor(a1, 16); a1 += __shfl_xor(a1, 32);
  a2 += __shfl_xor(a2, 16); a2 += __shfl_xor(a2, 32);
  a3 += __shfl_xor(a3, 16); a3 += __shfl_xor(a3, 32);
  // self loop
  {
    float lg = als_s + aldn + loopat[n] * ce;
    lg = (lg >= 0.f) ? lg : NEG_SLOPE * lg;
    float nm = fmaxf(m, lg);
    float sc = __expf(m - nm);
    float p  = __expf(lg - nm);
    ssum = ssum * sc + p;
    a0 = a0 * sc + p * s01.x;
    a1 = a1 * sc + p * s01.y;
    a2 = a2 * sc + p * s23.x;
    a3 = a3 * sc + p * s23.y;
  }
  float inv = 1.0f / ssum;
  float4 b4 = ((const float4*)bias)[i];
  float4 g4 = ((const float4*)gamma)[i];
  float4 be4 = ((const float4*)beta)[i];
  float4 rm4 = ((const float4*)rm)[i];
  float4 rv4 = ((const float4*)rv)[i];
  float o0 = a0 * inv + b4.x, o1 = a1 * inv + b4.y;
  float o2 = a2 * inv + b4.z, o3 = a3 * inv + b4.w;
  o0 = (o0 - rm4.x) * (g4.x * rsqrtf(rv4.x + BN_EPS)) + be4.x;
  o1 = (o1 - rm4.y) * (g4.y * rsqrtf(rv4.y + BN_EPS)) + be4.y;
  o2 = (o2 - rm4.z) * (g4.z * rsqrtf(rv4.z + BN_EPS)) + be4.z;
  o3 = (o3 - rm4.w) * (g4.w * rsqrtf(rv4.w + BN_EPS)) + be4.w;
  o0 = (o0 > 0.f) ? o0 : expm1f(o0);
  o1 = (o1 > 0.f) ? o1 : expm1f(o1);
  o2 = (o2 > 0.f) ? o2 : expm1f(o2);
  o3 = (o3 > 0.f) ? o3 : expm1f(o3);
  if (q == 0)
    ((float4*)(h2 + (size_t)n * GH))[i] = make_float4(o0, o1, o2, o3);
}

// ---------------- GEMM2: h2m = h2 @ W2 (bf16 rows) ----------------
__global__ __launch_bounds__(256) void gemm2_kernel(
    const float* __restrict__ x, const float* __restrict__ W2,
    ushort_t* __restrict__ h2mb) {
  __shared__ float w[HIDDEN * HIDDEN];   // 16 KB
  for (int i = threadIdx.x; i < HIDDEN * HIDDEN / 4; i += blockDim.x)
    ((float4*)w)[i] = ((const float4*)W2)[i];
  __syncthreads();
  int lane = threadIdx.x & 63;
  int waveG = __builtin_amdgcn_readfirstlane((blockIdx.x * blockDim.x + threadIdx.x) >> 6);
  int nWaves = (gridDim.x * blockDim.x) >> 6;
  for (int base = waveG * 4; base < N_NODES; base += nWaves * 4) {
    float acc[4] = {0.f, 0.f, 0.f, 0.f};
    #pragma unroll 8
    for (int k = 0; k < HIDDEN; ++k) {
      float wv = w[k * HIDDEN + lane];
      #pragma unroll
      for (int j = 0; j < 4; ++j)
        acc[j] = fmaf(x[(size_t)(base + j) * HIDDEN + k], wv, acc[j]);
    }
    #pragma unroll
    for (int j = 0; j < 4; ++j)
      h2mb[(size_t)(base + j) * HIDDEN + lane] = f2bf(acc[j]);
  }
}

// ---------------- conv2 (heads=1): single-touch 4-edge-batched gather ----------------
__global__ __launch_bounds__(256) void conv2_kernel(
    const ushort_t* __restrict__ h2mb,
    const float* __restrict__ asrc, const float* __restrict__ adst,
    const float* __restrict__ We, const float* __restrict__ ae,
    const int* __restrict__ rowptr,
    const int* __restrict__ csr_src, const float* __restrict__ csr_ea,
    const float* __restrict__ loopat, const float* __restrict__ bias,
    const float* __restrict__ gamma, const float* __restrict__ beta,
    const float* __restrict__ rm, const float* __restrict__ rv,
    const int* __restrict__ batch,
    float* __restrict__ pool, int* __restrict__ cntg) {
  __shared__ int   src_lds[4][64];
  __shared__ float ea_lds[4][64];
  int l = threadIdx.x & 63;
  int w = threadIdx.x >> 6;
  int n = blockIdx.x * 4 + w;
  if (n >= N_NODES) return;
  int i = l & 15;
  int q = l >> 4;
  const float4 as4 = ((const float4*)asrc)[i];
  const float4 ad4 = ((const float4*)adst)[i];
  float4 we4 = ((const float4*)We)[i];
  float4 ae4 = ((const float4*)ae)[i];
  float ce = we4.x*ae4.x + we4.y*ae4.y + we4.z*ae4.z + we4.w*ae4.w;
  ce += __shfl_xor(ce, 1); ce += __shfl_xor(ce, 2);
  ce += __shfl_xor(ce, 4); ce += __shfl_xor(ce, 8);   // full 64-dim coeff
  const uint2* tab = (const uint2*)h2mb;               // row = 16 x uint2
  uint2 uself = tab[(size_t)n * 16 + i];
  float2 s01 = upk(uself.x), s23 = upk(uself.y);
  float als_s = s01.x*as4.x + s01.y*as4.y + s23.x*as4.z + s23.y*as4.w;
  als_s += __shfl_xor(als_s, 1); als_s += __shfl_xor(als_s, 2);
  als_s += __shfl_xor(als_s, 4); als_s += __shfl_xor(als_s, 8);
  float aldn  = s01.x*ad4.x + s01.y*ad4.y + s23.x*ad4.z + s23.y*ad4.w;
  aldn += __shfl_xor(aldn, 1); aldn += __shfl_xor(aldn, 2);
  aldn += __shfl_xor(aldn, 4); aldn += __shfl_xor(aldn, 8);
  int jb = rowptr[n], je = rowptr[n + 1];
  float m = -1e30f, ssum = 0.f;
  float a0 = 0.f, a1 = 0.f, a2 = 0.f, a3 = 0.f;
  for (int cb = jb; cb < je; cb += 64) {
    int cnt = je - cb; if (cnt > 64) cnt = 64;
    int idx = cb + l;
    bool vld = l < cnt;
    src_lds[w][l] = vld ? csr_src[idx] : 0;
    ea_lds[w][l]  = vld ? csr_ea[idx] : 0.f;
    int nb = (cnt + 3) >> 2;
    int j0 = q;
    int s0 = (j0 < cnt) ? src_lds[w][j0] : 0;
    uint2 rcur = tab[(size_t)s0 * 16 + i];
    for (int b = 0; b < nb; ++b) {
      uint2 rnext = rcur;
      if (b + 1 < nb) {
        int jn = ((b + 1) << 2) + q;
        int sn = (jn < cnt) ? src_lds[w][jn] : 0;
        rnext = tab[(size_t)sn * 16 + i];
      }
      int j = (b << 2) + q;
      bool val = j < cnt;
      float eav = val ? ea_lds[w][j] : 0.f;
      float2 p01 = upk(rcur.x), p23 = upk(rcur.y);
      float dp = p01.x*as4.x + p01.y*as4.y + p23.x*as4.z + p23.y*as4.w;
      dp += __shfl_xor(dp, 1); dp += __shfl_xor(dp, 2);
      dp += __shfl_xor(dp, 4); dp += __shfl_xor(dp, 8);   // als of this edge
      float lg = dp + aldn + eav * ce;
      lg = (lg >= 0.f) ? lg : NEG_SLOPE * lg;
      lg = val ? lg : -1e30f;
      float bm = fmaxf(lg, __shfl_xor(lg, 16));
      bm = fmaxf(bm, __shfl_xor(bm, 32));
      float nm = fmaxf(m, bm);
      float sc = __expf(m - nm);
      float p  = __expf(lg - nm);
      float ps = p;
      ps += __shfl_xor(ps, 16);
      ps += __shfl_xor(ps, 32);
      ssum = ssum * sc + ps;
      m = nm;
      a0 = a0 * sc + p * p01.x;
      a1 = a1 * sc + p * p01.y;
      a2 = a2 * sc + p * p23.x;
      a3 = a3 * sc + p * p23.y;
      rcur = rnext;
    }
  }
  a0 += __shfl_xor(a0, 16); a0 += __shfl_xor(a0, 32);
  a1 += __shfl_xor(a1, 16); a1 += __shfl_xor(a1, 32);
  a2 += __shfl_xor(a2, 16); a2 += __shfl_xor(a2, 32);
  a3 += __shfl_xor(a3, 16); a3 += __shfl_xor(a3, 32);
  {
    float lg = als_s + aldn + loopat[n] * ce;
    lg = (lg >= 0.f) ? lg : NEG_SLOPE * lg;
    float nm = fmaxf(m, lg);
    float sc = __expf(m - nm);
    float p  = __expf(lg - nm);
    ssum = ssum * sc + p;
    a0 = a0 * sc + p * s01.x;
    a1 = a1 * sc + p * s01.y;
    a2 = a2 * sc + p * s23.x;
    a3 = a3 * sc + p * s23.y;
  }
  float inv = 1.0f / ssum;
  float4 b4 = ((const float4*)bias)[i];
  float4 g4 = ((const float4*)gamma)[i];
  float4 be4 = ((const float4*)beta)[i];
  float4 rm4 = ((const float4*)rm)[i];
  float4 rv4 = ((const float4*)rv)[i];
  float o0 = a0 * inv + b4.x, o1 = a1 * inv + b4.y;
  float o2 = a2 * inv + b4.z, o3 = a3 * inv + b4.w;
  o0 = (o0 - rm4.x) * (g4.x * rsqrtf(rv4.x + BN_EPS)) + be4.x;
  o1 = (o1 - rm4.y) * (g4.y * rsqrtf(rv4.y + BN_EPS)) + be4.y;
  o2 = (o2 - rm4.z) * (g4.z * rsqrtf(rv4.z + BN_EPS)) + be4.z;
  o3 = (o3 - rm4.w) * (g4.w * rsqrtf(rv4.w + BN_EPS)) + be4.w;
  o0 = (o0 > 0.f) ? o0 : expm1f(o0);
  o1 = (o1 > 0.f) ? o1 : expm1f(o1);
  o2 = (o2 > 0.f) ? o2 : expm1f(o2);
  o3 = (o3 > 0.f) ? o3 : expm1f(o3);
  if (q == 0) {
    int b = batch[n];
    float* pp = pool + (size_t)b * HIDDEN + 4 * i;
    atomicAdd(pp + 0, o0);
    atomicAdd(pp + 1, o1);
    atomicAdd(pp + 2, o2);
    atomicAdd(pp + 3, o3);
    if (l == 0) atomicAdd(&cntg[b], 1);
  }
}

// ---------------- classifier ----------------
__global__ __launch_bounds__(640) void final_kernel(
    const float* __restrict__ pool, const int* __restrict__ cntg,
    const float* __restrict__ Wc, const float* __restrict__ bc,
    float* __restrict__ out) {
  int t = threadIdx.x;
  if (t >= NBATCH * NC) return;
  int b = t / NC, c = t - b * NC;
  float inv = 1.0f / fmaxf((float)cntg[b], 1.0f);
  float s = bc[c];
  #pragma unroll
  for (int d = 0; d < HIDDEN; ++d)
    s = fmaf(pool[b * HIDDEN + d] * inv, Wc[d * NC + c], s);
  out[t] = s;
}

extern "C" void kernel_launch(void* const* d_in, const int* in_sizes, int n_in,
                              void* d_out, int out_size, void* d_ws, size_t ws_size,
                              hipStream_t stream) {
  const float* x     = (const float*)d_in[0];
  const float* raw   = (const float*)d_in[1];
  const int*   ei    = (const int*)  d_in[2];
  const int*   batch = (const int*)  d_in[3];
  const float* W1    = (const float*)d_in[4];
  const float* asrc1 = (const float*)d_in[5];
  const float* adst1 = (const float*)d_in[6];
  const float* We1   = (const float*)d_in[7];
  const float* ae1   = (const float*)d_in[8];
  const float* b1    = (const float*)d_in[9];
  const float* g1    = (const float*)d_in[10];
  const float* be1   = (const float*)d_in[11];
  const float* rm1   = (const float*)d_in[12];
  const float* rv1   = (const float*)d_in[13];
  const float* W2    = (const float*)d_in[14];
  const float* asrc2 = (const float*)d_in[15];
  const float* adst2 = (const float*)d_in[16];
  const float* We2   = (const float*)d_in[17];
  const float* ae2   = (const float*)d_in[18];
  const float* b2    = (const float*)d_in[19];
  const float* g2    = (const float*)d_in[20];
  const float* be2   = (const float*)d_in[21];
  const float* rm2   = (const float*)d_in[22];
  const float* rv2   = (const float*)d_in[23];
  const float* Wc    = (const float*)d_in[24];
  const float* bc    = (const float*)d_in[25];
  float* out = (float*)d_out;

  char* ws = (char*)d_ws;
  size_t off = 0;
  auto alloc = [&](size_t bytes) -> void* {
    void* p = ws + off;
    off += bytes;
    off = (off + 255) & ~(size_t)255;
    return p;
  };
  float*    ea      = (float*)   alloc((size_t)N_EDGES * 4);
  float*    csr_ea  = (float*)   alloc((size_t)N_EDGES * 4);
  int*      csr_src = (int*)     alloc((size_t)N_EDGES * 4);
  float*    easum   = (float*)   alloc((size_t)N_NODES * 4);
  int*      cnt     = (int*)     alloc((size_t)N_NODES * 4);
  int*      cnt2    = (int*)     alloc((size_t)N_NODES * 4);
  int*      rowptr  = (int*)     alloc((size_t)(N_NODES + 1) * 4);
  float*    loopat  = (float*)   alloc((size_t)N_NODES * 4);
  ushort_t* h1b     = (ushort_t*)alloc((size_t)N_NODES * GH * 2);
  float*    h2      = (float*)   alloc((size_t)N_NODES * GH * 4);
  ushort_t* h2mb    = (ushort_t*)alloc((size_t)N_NODES * HIDDEN * 2);
  int*      bsum    = (int*)     alloc(64 * 4);
  float*    pool    = (float*)   alloc((size_t)NBATCH * HIDDEN * 4);
  int*      cntg    = (int*)     alloc((size_t)NBATCH * 4);

  hipMemsetAsync(easum, 0, (size_t)N_NODES * 4, stream);
  hipMemsetAsync(cnt,   0, (size_t)N_NODES * 4, stream);
  hipMemsetAsync(cnt2,  0, (size_t)N_NODES * 4, stream);
  hipMemsetAsync(pool,  0, (size_t)NBATCH * HIDDEN * 4, stream);
  hipMemsetAsync(cntg,  0, (size_t)NBATCH * 4, stream);

  int egrid = (N_EDGES + 255) / 256;
  edge_kernel<<<egrid, 256, 0, stream>>>(ei, raw, ea, easum, cnt);
  scan_part<<<NTILES, SCAN_TPB, 0, stream>>>(cnt, easum, rowptr, loopat, bsum);
  scan_top<<<1, 64, 0, stream>>>(bsum, rowptr);
  scan_add<<<NTILES, SCAN_TPB, 0, stream>>>(rowptr, bsum);
  scatter_kernel<<<egrid, 256, 0, stream>>>(ei, ea, rowptr, cnt2, csr_src, csr_ea);

  gemm1_kernel<<<1024, 256, 0, stream>>>(x, W1, h1b);
  conv1_kernel<<<(N_NODES + 3) / 4, 256, 0, stream>>>(h1b, asrc1, adst1, We1, ae1,
      rowptr, csr_src, csr_ea, loopat, b1, g1, be1, rm1, rv1, h2);
  gemm2_kernel<<<1024, 256, 0, stream>>>(h2, W2, h2mb);
  conv2_kernel<<<(N_NODES + 3) / 4, 256, 0, stream>>>(h2mb, asrc2, adst2, We2, ae2,
      rowptr, csr_src, csr_ea, loopat, b2, g2, be2, rm2, rv2, batch, pool, cntg);
  final_kernel<<<1, 640, 0, stream>>>(pool, cntg, Wc, bc, out);
}